// Round 3
// baseline (1055.386 us; speedup 1.0000x reference)
//
#include <hip/hip_runtime.h>
#include <stdint.h>

#define N_EMB 8192
#define M_TOT 16384
#define TN 64
#define DELTA 4e-3f
#define LN_EPS 1e-5f

typedef _Float16 f16;
typedef f16 f16x8 __attribute__((ext_vector_type(8)));
typedef f16 f16x4 __attribute__((ext_vector_type(4)));
typedef float f32x4 __attribute__((ext_vector_type(4)));

// ws layout:
// [0,4MB) embd_h [8192][256] f16 ; [4MB,8MB) embd_th [256][8192] f16
// [8MB,+4) count ; [8MB+64,+64KB) list
#define WS_EMBD_H 0ul
#define WS_EMBD_TH (4ul << 20)
#define WS_COUNT (8ul << 20)
#define WS_LIST ((8ul << 20) + 64ul)

#define MFMA16(a, b, c) __builtin_amdgcn_mfma_f32_16x16x32_f16(a, b, c, 0, 0, 0)

// ---------------- prep: fp32 embd -> f16 in both layouts ----------------
__global__ __launch_bounds__(256) void prep_kernel(const float* __restrict__ embd,
                                                   f16* __restrict__ embd_h,
                                                   f16* __restrict__ embd_th,
                                                   unsigned* __restrict__ count) {
  if (blockIdx.x == 0 && threadIdx.x == 0) *count = 0u;
  __shared__ f16 tile[64][72];
  const int t = threadIdx.x;
  const int nb = (blockIdx.x >> 2) * 64;
  const int db = (blockIdx.x & 3) * 64;
  const int nl = t >> 2;
  const int dl = (t & 3) * 16;
  const float4* src = (const float4*)(embd + (size_t)(nb + nl) * 256 + db + dl);
  f16 vals[16];
#pragma unroll
  for (int q = 0; q < 4; ++q) {
    float4 v = src[q];
    vals[q * 4 + 0] = (f16)v.x;
    vals[q * 4 + 1] = (f16)v.y;
    vals[q * 4 + 2] = (f16)v.z;
    vals[q * 4 + 3] = (f16)v.w;
  }
  f16* dst = embd_h + (size_t)(nb + nl) * 256 + db + dl;
#pragma unroll
  for (int q = 0; q < 2; ++q) {
    f16x8 pack;
#pragma unroll
    for (int j = 0; j < 8; ++j) pack[j] = vals[q * 8 + j];
    *(f16x8*)(dst + q * 8) = pack;
  }
#pragma unroll
  for (int j = 0; j < 16; ++j) tile[nl][dl + j] = vals[j];
  __syncthreads();
  const int dl2 = t >> 2;
  const int nbase = (t & 3) * 16;
  f16* dstT = embd_th + (size_t)(db + dl2) * 8192 + nb + nbase;
#pragma unroll
  for (int q = 0; q < 2; ++q) {
    f16x8 pack;
#pragma unroll
    for (int j = 0; j < 8; ++j) pack[j] = tile[nbase + q * 8 + j][dl2];
    *(f16x8*)(dstT + q * 8) = pack;
  }
}

// ---------------- fused: LN + flash softmax-quantize ----------------
// Block = 256 thr = 4 waves. Block owns 32 rows; wave w owns N-quarter w.
// Chunk loop has ZERO barriers: B-frags read direct from global (L2-resident),
// P transposed through per-wave-private LDS.
// LDS: [0,16384) x-tile (32 rows x 256 f16, swizzled); reused in epilogue.
//      [16384,32768) P buffers, 4KB/wave.
__global__ __launch_bounds__(256, 2) void fused_kernel(
    const float* __restrict__ input, const float* __restrict__ ln_w,
    const float* __restrict__ ln_b, const f16* __restrict__ embd_h,
    const f16* __restrict__ embd_th, float* __restrict__ out_q,
    float* __restrict__ out_idx, unsigned* __restrict__ count,
    int* __restrict__ list) {
  __shared__ __align__(16) char lds[32768];
  const int tid = threadIdx.x;
  const int lane = tid & 63;
  const int w = tid >> 6;  // N-quarter
  const int cl = lane & 15;
  const int g = lane >> 4;
  const int R0 = blockIdx.x * 32;

  // ---- LN phase: 32 rows, 8 threads/row; fold 1/16 QK scale into x ----
  {
    const int r = tid >> 3;
    const int seg = tid & 7;
    const float* rowp = input + (size_t)(R0 + r) * 256 + seg * 32;
    float4 xv[8];
    float sm = 0.f, ssq = 0.f;
#pragma unroll
    for (int q = 0; q < 8; ++q) {
      xv[q] = ((const float4*)rowp)[q];
      sm += xv[q].x + xv[q].y + xv[q].z + xv[q].w;
      ssq += xv[q].x * xv[q].x + xv[q].y * xv[q].y + xv[q].z * xv[q].z +
             xv[q].w * xv[q].w;
    }
    sm += __shfl_xor(sm, 1);
    sm += __shfl_xor(sm, 2);
    sm += __shfl_xor(sm, 4);
    ssq += __shfl_xor(ssq, 1);
    ssq += __shfl_xor(ssq, 2);
    ssq += __shfl_xor(ssq, 4);
    const float mean = sm * (1.f / 256.f);
    const float var = ssq * (1.f / 256.f) - mean * mean;
    const float rstd = 1.0f / sqrtf(var + LN_EPS);
#pragma unroll
    for (int q = 0; q < 8; ++q) {
      const int d = seg * 32 + q * 4;
      float4 w4 = *(const float4*)(ln_w + d);
      float4 b4 = *(const float4*)(ln_b + d);
      f16x4 hv;
      hv[0] = (f16)((((xv[q].x - mean) * rstd) * w4.x + b4.x) * 0.0625f);
      hv[1] = (f16)((((xv[q].y - mean) * rstd) * w4.y + b4.y) * 0.0625f);
      hv[2] = (f16)((((xv[q].z - mean) * rstd) * w4.z + b4.z) * 0.0625f);
      hv[3] = (f16)((((xv[q].w - mean) * rstd) * w4.w + b4.w) * 0.0625f);
      const int byte = (r * 512 + d * 2) ^ ((r & 7) << 4);
      *(f16x4*)(lds + byte) = hv;
    }
  }
  __syncthreads();

  f32x4 acc[2][16] = {};
  float m_run[2][4], l_run[2][4], m2_run[2][4];
  int i1_run[2][4];
#pragma unroll
  for (int rf = 0; rf < 2; ++rf)
#pragma unroll
    for (int i = 0; i < 4; ++i) {
      m_run[rf][i] = -__builtin_inff();
      m2_run[rf][i] = -__builtin_inff();
      l_run[rf][i] = 0.f;
      i1_run[rf][i] = 0;
    }

  char* const Pb = lds + 16384 + w * 4096;
  const int nb0 = w * 2048;

  for (int c = 0; c < 32; ++c) {
    const int nb = nb0 + c * TN;
    // ---- QK^T: B-frags direct from global (L2), A-frags from LDS x-tile ----
    f32x4 Sf[2][4] = {};
    const f16* brow = embd_h + (size_t)(nb + cl) * 256 + g * 8;
#pragma unroll
    for (int kc = 0; kc < 8; ++kc) {
      const int u = ((kc * 4 + g) ^ (cl & 7)) << 4;
      f16x8 qa0 = *(const f16x8*)(lds + cl * 512 + u);
      f16x8 qa1 = *(const f16x8*)(lds + (16 + cl) * 512 + u);
#pragma unroll
      for (int fn = 0; fn < 4; ++fn) {
        f16x8 b = *(const f16x8*)(brow + (size_t)fn * 4096 + kc * 32);
        Sf[0][fn] = MFMA16(qa0, b, Sf[0][fn]);
        Sf[1][fn] = MFMA16(qa1, b, Sf[1][fn]);
      }
    }

    // ---- online softmax + top-2 + P write ----
    int grow = 0;
    float alpha[2][4];
#pragma unroll
    for (int rf = 0; rf < 2; ++rf) {
      float sv[4][4];
#pragma unroll
      for (int fn = 0; fn < 4; ++fn)
#pragma unroll
        for (int i = 0; i < 4; ++i) sv[i][fn] = Sf[rf][fn][i];
#pragma unroll
      for (int i = 0; i < 4; ++i) {
        const float a0 = sv[i][0], a1 = sv[i][1], a2 = sv[i][2], a3 = sv[i][3];
        const int j0 = nb + cl, j1 = nb + 16 + cl, j2 = nb + 32 + cl,
                  j3 = nb + 48 + cl;
        float hi1, lo1, hi2, lo2;
        int ii1, ii2;
        if (a1 > a0) { hi1 = a1; ii1 = j1; lo1 = a0; }
        else { hi1 = a0; ii1 = j0; lo1 = a1; }
        if (a3 > a2) { hi2 = a3; ii2 = j3; lo2 = a2; }
        else { hi2 = a2; ii2 = j2; lo2 = a3; }
        float t1, t2;
        int ti;
        if (hi2 > hi1) { t1 = hi2; ti = ii2; t2 = fmaxf(lo2, hi1); }
        else { t1 = hi1; ti = ii1; t2 = fmaxf(lo1, hi2); }
#pragma unroll
        for (int mk = 1; mk <= 8; mk <<= 1) {
          const float ov1 = __shfl_xor(t1, mk);
          const int oi = __shfl_xor(ti, mk);
          const float ov2 = __shfl_xor(t2, mk);
          if (ov1 > t1) { t2 = fmaxf(t1, ov2); t1 = ov1; ti = oi; }
          else { t2 = fmaxf(t2, ov1); }
        }
        const float mold = m_run[rf][i];
        if (t1 > mold) { m2_run[rf][i] = fmaxf(mold, t2); i1_run[rf][i] = ti; grow = 1; }
        else { m2_run[rf][i] = fmaxf(m2_run[rf][i], t1); }
        const float mnew = fmaxf(mold, t1);
        alpha[rf][i] = __expf(mold - mnew);
        m_run[rf][i] = mnew;
      }
#pragma unroll
      for (int i = 0; i < 4; ++i) {
        float rsum = 0.f;
#pragma unroll
        for (int fn = 0; fn < 4; ++fn) {
          const float p = __expf(sv[i][fn] - m_run[rf][i]);
          sv[i][fn] = p;
          rsum += p;
        }
        rsum += __shfl_xor(rsum, 1);
        rsum += __shfl_xor(rsum, 2);
        rsum += __shfl_xor(rsum, 4);
        rsum += __shfl_xor(rsum, 8);
        l_run[rf][i] = l_run[rf][i] * alpha[rf][i] + rsum;
      }
      // P write (wave-private LDS; conflict-free key (r>>1)&7)
#pragma unroll
      for (int i = 0; i < 4; ++i) {
        const int r = rf * 16 + g * 4 + i;
        const int kr = (r >> 1) & 7;
#pragma unroll
        for (int fn = 0; fn < 4; ++fn) {
          const int col = fn * 16 + cl;
          const int off = r * 128 + (((col >> 3) ^ kr) << 4) + ((col & 7) << 1);
          *(f16*)(Pb + off) = (f16)sv[i][fn];
        }
      }
    }
    if (__any(grow)) {
#pragma unroll
      for (int rf = 0; rf < 2; ++rf)
#pragma unroll
        for (int f = 0; f < 16; ++f) {
          acc[rf][f][0] *= alpha[rf][0];
          acc[rf][f][1] *= alpha[rf][1];
          acc[rf][f][2] *= alpha[rf][2];
          acc[rf][f][3] *= alpha[rf][3];
        }
    }
    // ---- PV: pa from private LDS, vb direct from global (L2) ----
    f16x8 pa[2][2];
#pragma unroll
    for (int rf = 0; rf < 2; ++rf)
#pragma unroll
      for (int k2 = 0; k2 < 2; ++k2) {
        const int row = rf * 16 + cl;
        pa[rf][k2] = *(const f16x8*)(
            Pb + row * 128 + (((k2 * 4 + g) ^ ((row >> 1) & 7)) << 4));
      }
#pragma unroll
    for (int f = 0; f < 16; ++f) {
      const f16* vrow = embd_th + (size_t)(f * 16 + cl) * 8192 + nb + g * 8;
      f16x8 vb0 = *(const f16x8*)(vrow);
      f16x8 vb1 = *(const f16x8*)(vrow + 32);
      acc[0][f] = MFMA16(pa[0][0], vb0, acc[0][f]);
      acc[1][f] = MFMA16(pa[1][0], vb0, acc[1][f]);
      acc[0][f] = MFMA16(pa[0][1], vb1, acc[0][f]);
      acc[1][f] = MFMA16(pa[1][1], vb1, acc[1][f]);
    }
  }

  // ---- epilogue: merge 4 N-quarters in-block ----
  __syncthreads();
  float4* stats = (float4*)lds;  // [4 waves][32 rows]
  if (cl == 0) {
#pragma unroll
    for (int rf = 0; rf < 2; ++rf)
#pragma unroll
      for (int i = 0; i < 4; ++i) {
        float4 st;
        st.x = m_run[rf][i];
        st.y = l_run[rf][i];
        st.z = m2_run[rf][i];
        st.w = (float)i1_run[rf][i];
        stats[w * 32 + rf * 16 + g * 4 + i] = st;
      }
  }
  __syncthreads();
  float a_self[2][4], inv[2][4];
#pragma unroll
  for (int rf = 0; rf < 2; ++rf)
#pragma unroll
    for (int i = 0; i < 4; ++i) {
      const int rl = rf * 16 + g * 4 + i;
      float4 s0 = stats[rl], s1 = stats[32 + rl], s2 = stats[64 + rl],
             s3 = stats[96 + rl];
      const float mstar = fmaxf(fmaxf(s0.x, s1.x), fmaxf(s2.x, s3.x));
      const float lstar = s0.y * __expf(s0.x - mstar) +
                          s1.y * __expf(s1.x - mstar) +
                          s2.y * __expf(s2.x - mstar) +
                          s3.y * __expf(s3.x - mstar);
      a_self[rf][i] = __expf(m_run[rf][i] - mstar);
      inv[rf][i] = 1.0f / lstar;
      if (w == 0 && cl == 0) {
        // winner fold (stream order preserves lowest-n on ties)
        float wm = s0.x, wm2 = s0.z;
        int wi = (int)s0.w;
        if (s1.x > wm) { wm2 = fmaxf(wm, s1.z); wm = s1.x; wi = (int)s1.w; }
        else { wm2 = fmaxf(wm2, s1.x); }
        if (s2.x > wm) { wm2 = fmaxf(wm, s2.z); wm = s2.x; wi = (int)s2.w; }
        else { wm2 = fmaxf(wm2, s2.x); }
        if (s3.x > wm) { wm2 = fmaxf(wm, s3.z); wm = s3.x; wi = (int)s3.w; }
        else { wm2 = fmaxf(wm2, s3.x); }
        const int r = R0 + rl;
        out_idx[r] = (float)wi;
        if (wm - wm2 <= DELTA) {
          const unsigned pos = atomicAdd(count, 1u);
          list[pos] = r;
        }
      }
    }
  __syncthreads();
  // acc tree-merge through LDS: regions A=[0,16K), B=[16K,32K)
  float* A = (float*)lds;
  float* Bf = (float*)(lds + 16384);
#pragma unroll
  for (int rf = 0; rf < 2; ++rf) {
    __syncthreads();
    if (w == 2) {
#pragma unroll
      for (int f = 0; f < 16; ++f)
#pragma unroll
        for (int i = 0; i < 4; ++i)
          A[(g * 4 + i) * 256 + f * 16 + cl] = acc[rf][f][i] * a_self[rf][i];
    }
    if (w == 3) {
#pragma unroll
      for (int f = 0; f < 16; ++f)
#pragma unroll
        for (int i = 0; i < 4; ++i)
          Bf[(g * 4 + i) * 256 + f * 16 + cl] = acc[rf][f][i] * a_self[rf][i];
    }
    __syncthreads();
    if (w == 0) {
#pragma unroll
      for (int f = 0; f < 16; ++f)
#pragma unroll
        for (int i = 0; i < 4; ++i)
          acc[rf][f][i] = acc[rf][f][i] * a_self[rf][i] +
                          A[(g * 4 + i) * 256 + f * 16 + cl];
    }
    if (w == 1) {
#pragma unroll
      for (int f = 0; f < 16; ++f)
#pragma unroll
        for (int i = 0; i < 4; ++i)
          acc[rf][f][i] = acc[rf][f][i] * a_self[rf][i] +
                          Bf[(g * 4 + i) * 256 + f * 16 + cl];
    }
    __syncthreads();
    if (w == 1) {
#pragma unroll
      for (int f = 0; f < 16; ++f)
#pragma unroll
        for (int i = 0; i < 4; ++i)
          A[(g * 4 + i) * 256 + f * 16 + cl] = acc[rf][f][i];
    }
    __syncthreads();
    if (w == 0) {
#pragma unroll
      for (int f = 0; f < 16; ++f)
#pragma unroll
        for (int i = 0; i < 4; ++i) {
          const int r = R0 + rf * 16 + g * 4 + i;
          out_q[(size_t)r * 256 + f * 16 + cl] =
              (acc[rf][f][i] + A[(g * 4 + i) * 256 + f * 16 + cl]) *
              inv[rf][i];
        }
    }
  }
}

// ---------------- refine: exact fp32 argmax for flagged rows ----------------
__global__ __launch_bounds__(256) void refine_kernel(
    const float* __restrict__ input, const float* __restrict__ ln_w,
    const float* __restrict__ ln_b, const float* __restrict__ embd,
    float* __restrict__ out_idx, const unsigned* __restrict__ count,
    const int* __restrict__ list) {
  __shared__ float xr[2][256];
  __shared__ float redv[256];
  __shared__ int redi[256];
  __shared__ float stat[8];
  const int tid = threadIdx.x;
  const unsigned cnt = *count;
  for (unsigned t = blockIdx.x; t * 2u < cnt; t += gridDim.x) {
    const unsigned rem = cnt - t * 2u;
    const int nrows = rem >= 2u ? 2 : 1;
    for (int rr = 0; rr < 2; ++rr) {
      const int row = list[t * 2u + (unsigned)(rr < nrows ? rr : 0)];
      const float v = input[(size_t)row * 256 + tid];
      float s = v, ss = v * v;
#pragma unroll
      for (int mk = 1; mk <= 32; mk <<= 1) {
        s += __shfl_xor(s, mk);
        ss += __shfl_xor(ss, mk);
      }
      if ((tid & 63) == 0) {
        stat[tid >> 6] = s;
        stat[4 + (tid >> 6)] = ss;
      }
      __syncthreads();
      const float S_ = stat[0] + stat[1] + stat[2] + stat[3];
      const float SS = stat[4] + stat[5] + stat[6] + stat[7];
      const float mean = S_ * (1.f / 256.f);
      const float var = SS * (1.f / 256.f) - mean * mean;
      const float rstd = 1.0f / sqrtf(var + LN_EPS);
      xr[rr][tid] = (v - mean) * rstd * ln_w[tid] + ln_b[tid];
      __syncthreads();
    }
    float b0 = -__builtin_inff(), b1 = -__builtin_inff();
    int i0 = 0, i1_ = 0;
    for (int n = tid; n < 8192; n += 256) {
      const float4* e4 = (const float4*)(embd + (size_t)n * 256);
      float d0 = 0.f, d1 = 0.f;
#pragma unroll 8
      for (int q = 0; q < 64; ++q) {
        const float4 e = e4[q];
        const float4 x0 = *(const float4*)&xr[0][q * 4];
        const float4 x1 = *(const float4*)&xr[1][q * 4];
        d0 += x0.x * e.x + x0.y * e.y + x0.z * e.z + x0.w * e.w;
        d1 += x1.x * e.x + x1.y * e.y + x1.z * e.z + x1.w * e.w;
      }
      if (d0 > b0) { b0 = d0; i0 = n; }
      if (d1 > b1) { b1 = d1; i1_ = n; }
    }
    for (int rr = 0; rr < nrows; ++rr) {
      __syncthreads();
      redv[tid] = rr ? b1 : b0;
      redi[tid] = rr ? i1_ : i0;
      __syncthreads();
      for (int off = 128; off > 0; off >>= 1) {
        if (tid < off) {
          const float ov = redv[tid + off];
          const int oi = redi[tid + off];
          if (ov > redv[tid] || (ov == redv[tid] && oi < redi[tid])) {
            redv[tid] = ov;
            redi[tid] = oi;
          }
        }
        __syncthreads();
      }
      if (tid == 0) out_idx[list[t * 2u + rr]] = (float)redi[0];
    }
  }
}

extern "C" void kernel_launch(void* const* d_in, const int* in_sizes, int n_in,
                              void* d_out, int out_size, void* d_ws,
                              size_t ws_size, hipStream_t stream) {
  (void)in_sizes;
  (void)n_in;
  (void)out_size;
  (void)ws_size;
  const float* input = (const float*)d_in[0];
  const float* ln_w = (const float*)d_in[1];
  const float* ln_b = (const float*)d_in[2];
  const float* embd = (const float*)d_in[3];
  float* out_q = (float*)d_out;
  float* out_idx = out_q + (size_t)M_TOT * 256;
  char* ws = (char*)d_ws;
  f16* embd_h = (f16*)(ws + WS_EMBD_H);
  f16* embd_th = (f16*)(ws + WS_EMBD_TH);
  unsigned* count = (unsigned*)(ws + WS_COUNT);
  int* list = (int*)(ws + WS_LIST);

  prep_kernel<<<512, 256, 0, stream>>>(embd, embd_h, embd_th, count);
  fused_kernel<<<M_TOT / 32, 256, 0, stream>>>(input, ln_w, ln_b, embd_h,
                                               embd_th, out_q, out_idx, count,
                                               list);
  refine_kernel<<<128, 256, 0, stream>>>(input, ln_w, ln_b, embd, out_idx,
                                         count, list);
}

// Round 4
// 761.925 us; speedup vs baseline: 1.3852x; 1.3852x over previous
//
#include <hip/hip_runtime.h>
#include <stdint.h>

#define N_EMB 8192
#define M_TOT 16384
#define DELTA 6e-3f   // top-2 gap threshold in log2-units
#define LN_EPS 1e-5f
#define SCL 0.09016994f  // 0.0625 * log2(e): logits in log2 units

typedef _Float16 f16;
typedef f16 f16x8 __attribute__((ext_vector_type(8)));
typedef f16 f16x4 __attribute__((ext_vector_type(4)));
typedef float f32x16 __attribute__((ext_vector_type(16)));
typedef unsigned uint32x4 __attribute__((ext_vector_type(4)));

// ws layout:
// [0,4MB) embd_h [8192][256] f16 ; [4MB,8MB) embd_th [256][8192] f16
// [8MB,+4) count ; [8MB+64,+64KB) list
#define WS_EMBD_H 0ul
#define WS_EMBD_TH (4ul << 20)
#define WS_COUNT (8ul << 20)
#define WS_LIST ((8ul << 20) + 64ul)

#define MFMA32(a, b, c) __builtin_amdgcn_mfma_f32_32x32x16_f16(a, b, c, 0, 0, 0)

// ---------------- prep: fp32 embd -> f16 in both layouts ----------------
__global__ __launch_bounds__(256) void prep_kernel(const float* __restrict__ embd,
                                                   f16* __restrict__ embd_h,
                                                   f16* __restrict__ embd_th,
                                                   unsigned* __restrict__ count) {
  if (blockIdx.x == 0 && threadIdx.x == 0) *count = 0u;
  __shared__ f16 tile[64][72];
  const int t = threadIdx.x;
  const int nb = (blockIdx.x >> 2) * 64;
  const int db = (blockIdx.x & 3) * 64;
  const int nl = t >> 2;
  const int dl = (t & 3) * 16;
  const float4* src = (const float4*)(embd + (size_t)(nb + nl) * 256 + db + dl);
  f16 vals[16];
#pragma unroll
  for (int q = 0; q < 4; ++q) {
    float4 v = src[q];
    vals[q * 4 + 0] = (f16)v.x;
    vals[q * 4 + 1] = (f16)v.y;
    vals[q * 4 + 2] = (f16)v.z;
    vals[q * 4 + 3] = (f16)v.w;
  }
  f16* dst = embd_h + (size_t)(nb + nl) * 256 + db + dl;
#pragma unroll
  for (int q = 0; q < 2; ++q) {
    f16x8 pack;
#pragma unroll
    for (int j = 0; j < 8; ++j) pack[j] = vals[q * 8 + j];
    *(f16x8*)(dst + q * 8) = pack;
  }
#pragma unroll
  for (int j = 0; j < 16; ++j) tile[nl][dl + j] = vals[j];
  __syncthreads();
  const int dl2 = t >> 2;
  const int nbase = (t & 3) * 16;
  f16* dstT = embd_th + (size_t)(db + dl2) * 8192 + nb + nbase;
#pragma unroll
  for (int q = 0; q < 2; ++q) {
    f16x8 pack;
#pragma unroll
    for (int j = 0; j < 8; ++j) pack[j] = tile[nbase + q * 8 + j][dl2];
    *(f16x8*)(dstT + q * 8) = pack;
  }
}

// ---------------- fused: LN + flash softmax-quantize ----------------
// 256 blocks x 512 thr. Block = 64 rows = 2 q-groups x 32. 8 waves:
// qg = w>>2, nq = w&3 (n-quarter of 2048). Pairs (qg0,qg1) of same nq read
// identical embd addresses in lockstep -> L1/MSHR sharing. Swapped QK^T
// (mfma(K,Q)) keeps softmax fully in-register. Q frags in LDS (32KB, CF).
__global__ __launch_bounds__(512, 2) void fused_kernel(
    const float* __restrict__ input, const float* __restrict__ ln_w,
    const float* __restrict__ ln_b, const f16* __restrict__ embd_h,
    const f16* __restrict__ embd_th, float* __restrict__ out_q,
    float* __restrict__ out_idx, unsigned* __restrict__ count,
    int* __restrict__ list) {
  __shared__ __align__(16) char lds[65536];
  const int tid = threadIdx.x;
  const int lane = tid & 63;
  const int w = tid >> 6;
  const int qg = w >> 2;
  const int nq = w & 3;
  const int q = lane & 31;
  const int hi = lane >> 5;
  const int R0 = blockIdx.x * 64;

  // ---- LN: 64 rows, 8 thr/row; write Q into B-frag LDS layout ----
  {
    const int r = tid >> 3;
    const int seg = tid & 7;
    const float* rowp = input + (size_t)(R0 + r) * 256 + seg * 32;
    float4 xv[8];
    float sm = 0.f, ssq = 0.f;
#pragma unroll
    for (int qd = 0; qd < 8; ++qd) {
      xv[qd] = ((const float4*)rowp)[qd];
      sm += xv[qd].x + xv[qd].y + xv[qd].z + xv[qd].w;
      ssq += xv[qd].x * xv[qd].x + xv[qd].y * xv[qd].y + xv[qd].z * xv[qd].z +
             xv[qd].w * xv[qd].w;
    }
    sm += __shfl_xor(sm, 1);
    sm += __shfl_xor(sm, 2);
    sm += __shfl_xor(sm, 4);
    ssq += __shfl_xor(ssq, 1);
    ssq += __shfl_xor(ssq, 2);
    ssq += __shfl_xor(ssq, 4);
    const float mean = sm * (1.f / 256.f);
    const float var = ssq * (1.f / 256.f) - mean * mean;
    const float rstd = 1.0f / sqrtf(var + LN_EPS);
#pragma unroll
    for (int qd = 0; qd < 8; ++qd) {
      const int d0 = seg * 32 + qd * 4;
      float4 w4 = *(const float4*)(ln_w + d0);
      float4 b4 = *(const float4*)(ln_b + d0);
      f16x4 hv;
      hv[0] = (f16)((((xv[qd].x - mean) * rstd) * w4.x + b4.x) * SCL);
      hv[1] = (f16)((((xv[qd].y - mean) * rstd) * w4.y + b4.y) * SCL);
      hv[2] = (f16)((((xv[qd].z - mean) * rstd) * w4.z + b4.z) * SCL);
      hv[3] = (f16)((((xv[qd].w - mean) * rstd) * w4.w + b4.w) * SCL);
      // layout: [qg][kc][hi][q][j]  (16B per (kc,hi,q))
      const int off = (r >> 5) * 16384 + (d0 >> 4) * 1024 + ((d0 >> 3) & 1) * 512 +
                      (r & 31) * 16 + (d0 & 7) * 2;
      *(f16x4*)(lds + off) = hv;
    }
  }
  __syncthreads();

  f32x16 acc[8] = {};
  float m_run = 0.f, l_run = 0.f, mt1 = 0.f, mt2 = 0.f;
  int i1 = 0;
  const char* qbase = lds + qg * 16384 + hi * 512 + q * 16;

  for (int c = 0; c < 64; ++c) {
    const int nb = nq * 2048 + c * 32;
    __builtin_amdgcn_s_barrier();  // pace pair waves for L1 sharing
    // K half A (kc 0..7) + V half 1 (dt 0..3)
    const f16* kbase = embd_h + (size_t)(nb + q) * 256 + hi * 8;
    f16x8 ka[8];
#pragma unroll
    for (int kc = 0; kc < 8; ++kc) ka[kc] = *(const f16x8*)(kbase + kc * 16);
    f16x8 va[8];
#pragma unroll
    for (int dt = 0; dt < 4; ++dt)
#pragma unroll
      for (int ks = 0; ks < 2; ++ks)
        va[dt * 2 + ks] = *(const f16x8*)(embd_th + (size_t)(dt * 32 + q) * 8192 +
                                          nb + ks * 16 + hi * 8);
    f32x16 S = {};
#pragma unroll
    for (int kc = 0; kc < 8; ++kc) {
      f16x8 qf = *(const f16x8*)(qbase + kc * 1024);
      S = MFMA32(ka[kc], qf, S);
    }
    f16x8 kb[8];
#pragma unroll
    for (int kc = 0; kc < 8; ++kc) kb[kc] = *(const f16x8*)(kbase + 128 + kc * 16);
#pragma unroll
    for (int kc = 0; kc < 8; ++kc) {
      f16x8 qf = *(const f16x8*)(qbase + (kc + 8) * 1024);
      S = MFMA32(kb[kc], qf, S);
    }
    // V half 2 issue (latency hides under softmax)
    f16x8 vb[8];
#pragma unroll
    for (int dt = 0; dt < 4; ++dt)
#pragma unroll
      for (int ks = 0; ks < 2; ++ks)
        vb[dt * 2 + ks] = *(const f16x8*)(embd_th + (size_t)((dt + 4) * 32 + q) * 8192 +
                                          nb + ks * 16 + hi * 8);

    // ---- in-register softmax + top-2 (lane owns q = lane&31) ----
    const int nbh = nb + hi * 4;
    float t1 = S[0], t2 = -3.4e38f;
    int ti = nbh;
#pragma unroll
    for (int r = 1; r < 16; ++r) {
      const int nl = nbh + (r & 3) + 8 * (r >> 2);
      const float v = S[r];
      const bool gt = v > t1;
      t2 = gt ? t1 : fmaxf(t2, v);
      ti = gt ? nl : ti;
      t1 = gt ? v : t1;
    }
    {
      const float o1 = __shfl_xor(t1, 32);
      const float o2 = __shfl_xor(t2, 32);
      const int oi = __shfl_xor(ti, 32);
      if (o1 > t1) { t2 = fmaxf(t1, o2); t1 = o1; ti = oi; }
      else t2 = fmaxf(t2, o1);
    }
    if (c == 0) {
      m_run = t1; mt1 = t1; mt2 = t2; i1 = ti;
    } else {
      if (t1 > mt1) { mt2 = fmaxf(mt1, t2); mt1 = t1; i1 = ti; }
      else mt2 = fmaxf(mt2, t1);
      if (__any(t1 - m_run > 8.f)) {  // defer-max: ~never taken on this data
        const float mnew = fmaxf(m_run, t1);
        const float a = exp2f(m_run - mnew);
        l_run *= a;
        m_run = mnew;
        float av[16];
#pragma unroll
        for (int r = 0; r < 16; ++r)
          av[r] = __shfl(a, (r & 3) + 8 * (r >> 2) + hi * 4);
#pragma unroll
        for (int dt = 0; dt < 8; ++dt)
#pragma unroll
          for (int r = 0; r < 16; ++r) acc[dt][r] *= av[r];
      }
    }
    float P[16];
    float rs = 0.f;
#pragma unroll
    for (int r = 0; r < 16; ++r) {
      P[r] = exp2f(S[r] - m_run);
      rs += P[r];
    }
    l_run += rs;  // half-sum; cross-half merge at epilogue
    // ---- P -> f16 PA fragments (cvt_pkrtz + cross-half shfl) ----
    unsigned cc[8], xx[8];
#pragma unroll
    for (int i2 = 0; i2 < 8; ++i2) {
      auto pk = __builtin_amdgcn_cvt_pkrtz(P[2 * i2], P[2 * i2 + 1]);
      cc[i2] = __builtin_bit_cast(unsigned, pk);
    }
#pragma unroll
    for (int i2 = 0; i2 < 8; ++i2)
      xx[i2] = (unsigned)__shfl_xor((int)cc[i2], 32);
    uint32x4 u0, u1;
    u0[0] = hi ? xx[2] : cc[0];
    u0[1] = hi ? xx[3] : cc[1];
    u0[2] = hi ? cc[2] : xx[0];
    u0[3] = hi ? cc[3] : xx[1];
    u1[0] = hi ? xx[6] : cc[4];
    u1[1] = hi ? xx[7] : cc[5];
    u1[2] = hi ? cc[6] : xx[4];
    u1[3] = hi ? cc[7] : xx[5];
    const f16x8 pa0 = __builtin_bit_cast(f16x8, u0);
    const f16x8 pa1 = __builtin_bit_cast(f16x8, u1);
    // ---- PV ----
#pragma unroll
    for (int dt = 0; dt < 4; ++dt) {
      acc[dt] = MFMA32(pa0, va[dt * 2 + 0], acc[dt]);
      acc[dt] = MFMA32(pa1, va[dt * 2 + 1], acc[dt]);
    }
#pragma unroll
    for (int dt = 0; dt < 4; ++dt) {
      acc[dt + 4] = MFMA32(pa0, vb[dt * 2 + 0], acc[dt + 4]);
      acc[dt + 4] = MFMA32(pa1, vb[dt * 2 + 1], acc[dt + 4]);
    }
  }

  // ---- epilogue: merge 4 n-quarters per q-group ----
  __syncthreads();
  const float lf = l_run + __shfl_xor(l_run, 32);
  float4* statA = (float4*)lds;          // [qg][nq][q]
  int* statB = (int*)(lds + 4096);
  if (hi == 0) {
    statA[qg * 128 + nq * 32 + q] = make_float4(m_run, lf, mt1, mt2);
    statB[qg * 128 + nq * 32 + q] = i1;
  }
  __syncthreads();
  const float4 s0 = statA[qg * 128 + 0 * 32 + q];
  const float4 s1 = statA[qg * 128 + 1 * 32 + q];
  const float4 s2 = statA[qg * 128 + 2 * 32 + q];
  const float4 s3 = statA[qg * 128 + 3 * 32 + q];
  const float mstar = fmaxf(fmaxf(s0.x, s1.x), fmaxf(s2.x, s3.x));
  const float lstar = s0.y * exp2f(s0.x - mstar) + s1.y * exp2f(s1.x - mstar) +
                      s2.y * exp2f(s2.x - mstar) + s3.y * exp2f(s3.x - mstar);
  const float a_self = exp2f(m_run - mstar);
  const float inv = 1.0f / lstar;
  if (nq == 0 && hi == 0) {
    float wm = s0.z, wm2 = s0.w;
    int wi = statB[qg * 128 + q];
    if (s1.z > wm) { wm2 = fmaxf(wm, s1.w); wm = s1.z; wi = statB[qg * 128 + 32 + q]; }
    else wm2 = fmaxf(wm2, s1.z);
    if (s2.z > wm) { wm2 = fmaxf(wm, s2.w); wm = s2.z; wi = statB[qg * 128 + 64 + q]; }
    else wm2 = fmaxf(wm2, s2.z);
    if (s3.z > wm) { wm2 = fmaxf(wm, s3.w); wm = s3.z; wi = statB[qg * 128 + 96 + q]; }
    else wm2 = fmaxf(wm2, s3.z);
    const int row = R0 + qg * 32 + q;
    out_idx[row] = (float)wi;
    if (wm - wm2 <= DELTA) {
      const unsigned pos = atomicAdd(count, 1u);
      list[pos] = row;
    }
  }
  float av[16], ivr[16];
#pragma unroll
  for (int r = 0; r < 16; ++r) {
    const int qr = (r & 3) + 8 * (r >> 2) + hi * 4;
    av[r] = __shfl(a_self, qr);
    ivr[r] = __shfl(inv, qr);
  }
#pragma unroll
  for (int dt = 0; dt < 8; ++dt)
#pragma unroll
    for (int r = 0; r < 16; ++r) acc[dt][r] *= av[r];
  __syncthreads();
  float* region = (float*)(lds + qg * 32768);
#define MRG_ADDR(dt, r) (((r & 3) + 8 * (r >> 2) + hi * 4) * 256 + dt * 32 + q)
  if (nq == 1) {
#pragma unroll
    for (int dt = 0; dt < 8; ++dt)
#pragma unroll
      for (int r = 0; r < 16; ++r) region[MRG_ADDR(dt, r)] = acc[dt][r];
  }
  __syncthreads();
  if (nq == 0) {
#pragma unroll
    for (int dt = 0; dt < 8; ++dt)
#pragma unroll
      for (int r = 0; r < 16; ++r) acc[dt][r] += region[MRG_ADDR(dt, r)];
  }
  __syncthreads();
  if (nq == 3) {
#pragma unroll
    for (int dt = 0; dt < 8; ++dt)
#pragma unroll
      for (int r = 0; r < 16; ++r) region[MRG_ADDR(dt, r)] = acc[dt][r];
  }
  __syncthreads();
  if (nq == 2) {
#pragma unroll
    for (int dt = 0; dt < 8; ++dt)
#pragma unroll
      for (int r = 0; r < 16; ++r) acc[dt][r] += region[MRG_ADDR(dt, r)];
  }
  __syncthreads();
  if (nq == 2) {
#pragma unroll
    for (int dt = 0; dt < 8; ++dt)
#pragma unroll
      for (int r = 0; r < 16; ++r) region[MRG_ADDR(dt, r)] = acc[dt][r];
  }
  __syncthreads();
  if (nq == 0) {
#pragma unroll
    for (int dt = 0; dt < 8; ++dt)
#pragma unroll
      for (int r = 0; r < 16; ++r) {
        const int qr = (r & 3) + 8 * (r >> 2) + hi * 4;
        const float v = (acc[dt][r] + region[MRG_ADDR(dt, r)]) * ivr[r];
        out_q[(size_t)(R0 + qg * 32 + qr) * 256 + dt * 32 + q] = v;
      }
  }
#undef MRG_ADDR
}

// ---------------- refine: exact fp32 argmax for flagged rows ----------------
__global__ __launch_bounds__(256) void refine_kernel(
    const float* __restrict__ input, const float* __restrict__ ln_w,
    const float* __restrict__ ln_b, const float* __restrict__ embd,
    float* __restrict__ out_idx, const unsigned* __restrict__ count,
    const int* __restrict__ list) {
  __shared__ float xr[2][256];
  __shared__ float redv[256];
  __shared__ int redi[256];
  __shared__ float stat[8];
  const int tid = threadIdx.x;
  const unsigned cnt = *count;
  for (unsigned t = blockIdx.x; t * 2u < cnt; t += gridDim.x) {
    const unsigned rem = cnt - t * 2u;
    const int nrows = rem >= 2u ? 2 : 1;
    for (int rr = 0; rr < 2; ++rr) {
      const int row = list[t * 2u + (unsigned)(rr < nrows ? rr : 0)];
      const float v = input[(size_t)row * 256 + tid];
      float s = v, ss = v * v;
#pragma unroll
      for (int mk = 1; mk <= 32; mk <<= 1) {
        s += __shfl_xor(s, mk);
        ss += __shfl_xor(ss, mk);
      }
      if ((tid & 63) == 0) {
        stat[tid >> 6] = s;
        stat[4 + (tid >> 6)] = ss;
      }
      __syncthreads();
      const float S_ = stat[0] + stat[1] + stat[2] + stat[3];
      const float SS = stat[4] + stat[5] + stat[6] + stat[7];
      const float mean = S_ * (1.f / 256.f);
      const float var = SS * (1.f / 256.f) - mean * mean;
      const float rstd = 1.0f / sqrtf(var + LN_EPS);
      xr[rr][tid] = (v - mean) * rstd * ln_w[tid] + ln_b[tid];
      __syncthreads();
    }
    float b0 = -__builtin_inff(), b1 = -__builtin_inff();
    int i0 = 0, i1_ = 0;
    for (int n = tid; n < 8192; n += 256) {
      const float4* e4 = (const float4*)(embd + (size_t)n * 256);
      float d0 = 0.f, d1 = 0.f;
#pragma unroll 8
      for (int qd = 0; qd < 64; ++qd) {
        const float4 e = e4[qd];
        const float4 x0 = *(const float4*)&xr[0][qd * 4];
        const float4 x1 = *(const float4*)&xr[1][qd * 4];
        d0 += x0.x * e.x + x0.y * e.y + x0.z * e.z + x0.w * e.w;
        d1 += x1.x * e.x + x1.y * e.y + x1.z * e.z + x1.w * e.w;
      }
      if (d0 > b0) { b0 = d0; i0 = n; }
      if (d1 > b1) { b1 = d1; i1_ = n; }
    }
    for (int rr = 0; rr < nrows; ++rr) {
      __syncthreads();
      redv[tid] = rr ? b1 : b0;
      redi[tid] = rr ? i1_ : i0;
      __syncthreads();
      for (int off = 128; off > 0; off >>= 1) {
        if (tid < off) {
          const float ov = redv[tid + off];
          const int oi = redi[tid + off];
          if (ov > redv[tid] || (ov == redv[tid] && oi < redi[tid])) {
            redv[tid] = ov;
            redi[tid] = oi;
          }
        }
        __syncthreads();
      }
      if (tid == 0) out_idx[list[t * 2u + rr]] = (float)redi[0];
    }
  }
}

extern "C" void kernel_launch(void* const* d_in, const int* in_sizes, int n_in,
                              void* d_out, int out_size, void* d_ws,
                              size_t ws_size, hipStream_t stream) {
  (void)in_sizes;
  (void)n_in;
  (void)out_size;
  (void)ws_size;
  const float* input = (const float*)d_in[0];
  const float* ln_w = (const float*)d_in[1];
  const float* ln_b = (const float*)d_in[2];
  const float* embd = (const float*)d_in[3];
  float* out_q = (float*)d_out;
  float* out_idx = out_q + (size_t)M_TOT * 256;
  char* ws = (char*)d_ws;
  f16* embd_h = (f16*)(ws + WS_EMBD_H);
  f16* embd_th = (f16*)(ws + WS_EMBD_TH);
  unsigned* count = (unsigned*)(ws + WS_COUNT);
  int* list = (int*)(ws + WS_LIST);

  prep_kernel<<<512, 256, 0, stream>>>(embd, embd_h, embd_th, count);
  fused_kernel<<<256, 512, 0, stream>>>(input, ln_w, ln_b, embd_h, embd_th,
                                        out_q, out_idx, count, list);
  refine_kernel<<<128, 256, 0, stream>>>(input, ln_w, ln_b, embd, out_idx,
                                         count, list);
}